// Round 15
// baseline (181.198 us; speedup 1.0000x reference)
//
#include <hip/hip_runtime.h>
#include <hip/hip_bf16.h>

// SDPA B=2 H=16 S=2048 D=64, outputs (out, attn) f32.
// R15 = R11 (168.5us) + one-time bf16 pre-conversion of K and V^T into d_ws,
// stored as the exact swizzled 8KB-per-chunk LDS images. Main kernel staging
// becomes a linear 16B/thread copy (global_load_dwordx4 -> ds_write_b128):
// no per-chunk cvt VALU, and K/V demand fetch halves (bf16).
// Bit-identical math to R11 (same RNE cvt, same MFMA order).
// Fallback to the R11 kernel if ws_size < 16MB.

#define S_LEN 2048
#define DH 64
#define QT 128
#define NCH (S_LEN / 64)

typedef __attribute__((ext_vector_type(8))) short  s16x8;
typedef __attribute__((ext_vector_type(4))) short  s16x4;
typedef __attribute__((ext_vector_type(8))) __bf16 bf16x8;
typedef __attribute__((ext_vector_type(4))) float  f32x4;
typedef __attribute__((ext_vector_type(2))) unsigned int u32x2;

__device__ __forceinline__ short f2bf(float x) {
    __hip_bfloat16 h = __float2bfloat16(x);   // RNE
    return *reinterpret_cast<short*>(&h);
}
__device__ __forceinline__ unsigned pack2(float a, float b) {
    return (unsigned)(unsigned short)f2bf(a) | ((unsigned)(unsigned short)f2bf(b) << 16);
}
__device__ __forceinline__ bf16x8 ldfrag(const short* p) {
    s16x8 t = *(const s16x8*)p;               // ds_read_b128
    return __builtin_bit_cast(bf16x8, t);
}
// XOR swizzles (G4): [rows][64] tiles.
__device__ __forceinline__ int SW (int r, int c) { return r * 64 + (c ^ ((r & 7) << 3)); }
__device__ __forceinline__ int SWF(int r, int c) { return r * 64 + (c ^ ((r & 7) << 3)); }

// ---------- pre-pass: build swizzled bf16 images of K and V^T in ws ----------
__global__ __launch_bounds__(256, 4) void prep_kernel(
    const float* __restrict__ k, const float* __restrict__ v,
    short* __restrict__ wsK, short* __restrict__ wsVt)
{
    __shared__ float tile[64 * 65];     // f32 V chunk, padded (65 odd -> no conflicts)
    const int tid = threadIdx.x;
    const int blk = blockIdx.x;         // 0..1023
    const int bh = blk >> 5;
    const int c  = blk & 31;

    const float* kc = k + (((size_t)bh * S_LEN) + c * 64) * DH;
    const float* vc = v + (((size_t)bh * S_LEN) + c * 64) * DH;
    short* dstK = wsK  + ((size_t)bh * 32 + c) * 4096;
    short* dstV = wsVt + ((size_t)bh * 32 + c) * 4096;

    const int r  = tid >> 2;            // 0..63
    const int d0 = (tid & 3) * 16;      // 0,16,32,48
    {   // K: row-major image, swizzled
        const float* src = kc + r * DH + d0;
        const float4 a0 = *(const float4*)(src);
        const float4 a1 = *(const float4*)(src + 4);
        const float4 a2 = *(const float4*)(src + 8);
        const float4 a3 = *(const float4*)(src + 12);
        s16x8 v0, v1;
        v0[0]=f2bf(a0.x); v0[1]=f2bf(a0.y); v0[2]=f2bf(a0.z); v0[3]=f2bf(a0.w);
        v0[4]=f2bf(a1.x); v0[5]=f2bf(a1.y); v0[6]=f2bf(a1.z); v0[7]=f2bf(a1.w);
        v1[0]=f2bf(a2.x); v1[1]=f2bf(a2.y); v1[2]=f2bf(a2.z); v1[3]=f2bf(a2.w);
        v1[4]=f2bf(a3.x); v1[5]=f2bf(a3.y); v1[6]=f2bf(a3.z); v1[7]=f2bf(a3.w);
        *(s16x8*)&dstK[SW(r, d0)]     = v0;
        *(s16x8*)&dstK[SW(r, d0 + 8)] = v1;
    }
    {   // V: stage f32 chunk to LDS (coalesced), transpose below
        const float* src = vc + r * DH + d0;
        *(float4*)&tile[r * 65 + d0]      = *(const float4*)(src);
        *(float4*)&tile[r * 65 + d0 + 4]  = *(const float4*)(src + 4);
        *(float4*)&tile[r * 65 + d0 + 8]  = *(const float4*)(src + 8);
        *(float4*)&tile[r * 65 + d0 + 12] = *(const float4*)(src + 12);
    }
    __syncthreads();
    {   // V^T image: row d holds V[*, d], swizzled
        const int d  = tid >> 2;        // 0..63
        const int kb = (tid & 3) * 16;  // 0,16,32,48
        s16x8 w0, w1;
#pragma unroll
        for (int i = 0; i < 8; ++i) w0[i] = f2bf(tile[(kb + i) * 65 + d]);
#pragma unroll
        for (int i = 0; i < 8; ++i) w1[i] = f2bf(tile[(kb + 8 + i) * 65 + d]);
        *(s16x8*)&dstV[SW(d, kb)]     = w0;
        *(s16x8*)&dstV[SW(d, kb + 8)] = w1;
    }
}

// ---------- main kernel: staging = linear 16B/thread copy of images ----------
__global__ __launch_bounds__(512, 4) void sdpa_main(
    const float* __restrict__ q, const short* __restrict__ wsK,
    const short* __restrict__ wsVt, const int* __restrict__ mask,
    float* __restrict__ out, float* __restrict__ attn)
{
    __shared__ __align__(16) short shK[2][4096];       // 16 KB dbuf (image)
    __shared__ __align__(16) short shVt[2][4096];      // 16 KB dbuf (image)
    __shared__ __align__(16) float shPT[8][16 * 64];   // 32 KB, per-wave P f32
    __shared__ char shMask[S_LEN];                     // 2 KB

    const int tid  = threadIdx.x;
    const int lane = tid & 63;
    const int w    = tid >> 6;
    const int l15  = lane & 15;
    const int lg   = lane >> 4;

    const int bh = blockIdx.y;
    const int q0 = blockIdx.x * QT;
    const int b  = bh >> 4;

    const float* qbase = q + ((size_t)bh * S_LEN + q0) * DH;
    const short* wsKbh = wsK  + (size_t)bh * 32 * 4096;
    const short* wsVbh = wsVt + (size_t)bh * 32 * 4096;
    float* attnbh = attn + (size_t)bh * S_LEN * S_LEN;

    for (int i = tid; i < S_LEN; i += 512)
        shMask[i] = (char)(mask[b * S_LEN + i] != 0);

    // Q fragments straight to registers (scaled 1/8, bf16)
    const int qrow = w * 16 + l15;
    bf16x8 qf0, qf1;
    {
        const float* qp = qbase + qrow * DH + 8 * lg;
        const float4 a0 = *(const float4*)(qp);
        const float4 a1 = *(const float4*)(qp + 4);
        const float4 b0 = *(const float4*)(qp + 32);
        const float4 b1 = *(const float4*)(qp + 36);
        s16x8 t0, t1;
        t0[0]=f2bf(a0.x*0.125f); t0[1]=f2bf(a0.y*0.125f); t0[2]=f2bf(a0.z*0.125f); t0[3]=f2bf(a0.w*0.125f);
        t0[4]=f2bf(a1.x*0.125f); t0[5]=f2bf(a1.y*0.125f); t0[6]=f2bf(a1.z*0.125f); t0[7]=f2bf(a1.w*0.125f);
        t1[0]=f2bf(b0.x*0.125f); t1[1]=f2bf(b0.y*0.125f); t1[2]=f2bf(b0.z*0.125f); t1[3]=f2bf(b0.w*0.125f);
        t1[4]=f2bf(b1.x*0.125f); t1[5]=f2bf(b1.y*0.125f); t1[6]=f2bf(b1.z*0.125f); t1[7]=f2bf(b1.w*0.125f);
        qf0 = __builtin_bit_cast(bf16x8, t0);
        qf1 = __builtin_bit_cast(bf16x8, t1);
    }

    // linear image staging (reg-staged 16B/thread; swizzle pre-baked in ws)
    s16x8 kreg, vreg;
    auto loadKc = [&](int c) { kreg = *(const s16x8*)(wsKbh + (size_t)c * 4096 + tid * 8); };
    auto loadVc = [&](int c) { vreg = *(const s16x8*)(wsVbh + (size_t)c * 4096 + tid * 8); };
    auto putK = [&](int buf) { *(s16x8*)&shK[buf][tid * 8] = kreg; };
    auto putV = [&](int buf) { *(s16x8*)&shVt[buf][tid * 8] = vreg; };

    // ---------------- PASS A: row sumexp (fixed C=0), lane-local ----------------
    loadKc(0);
    putK(0);
    __syncthreads();

    float lacc = 0.f;
    for (int t = 0; t < NCH; ++t) {
        const int cur = t & 1;
        if (t + 1 < NCH) loadKc(t + 1);
        __syncthreads();
        const short* K = shK[cur];
        const int c0 = t * 64;
        f32x4 s[4] = {{0,0,0,0},{0,0,0,0},{0,0,0,0},{0,0,0,0}};
#pragma unroll
        for (int ct = 0; ct < 4; ++ct) {
            const int kc = ct * 16 + l15;
            bf16x8 kf = ldfrag(&K[SW(kc, 8 * lg)]);
            s[ct] = __builtin_amdgcn_mfma_f32_16x16x32_bf16(kf, qf0, s[ct], 0, 0, 0);
            kf = ldfrag(&K[SW(kc, 32 + 8 * lg)]);
            s[ct] = __builtin_amdgcn_mfma_f32_16x16x32_bf16(kf, qf1, s[ct], 0, 0, 0);
        }
#pragma unroll
        for (int ct = 0; ct < 4; ++ct) {
            const unsigned mw = *(const unsigned*)&shMask[c0 + ct * 16 + lg * 4];
#pragma unroll
            for (int r = 0; r < 4; ++r)
                lacc += ((mw >> (8 * r)) & 1u) ? __expf(s[ct][r]) : 0.f;
        }
        if (t + 1 < NCH) putK(cur ^ 1);
    }
    lacc += __shfl_xor(lacc, 16);
    lacc += __shfl_xor(lacc, 32);
    const float lnInvl = -__logf(lacc);

    // ---------------- PASS B: recompute, write attn, PV accumulate ----------------
    f32x4 oacc[4] = {{0,0,0,0},{0,0,0,0},{0,0,0,0},{0,0,0,0}};
    loadKc(0);
    loadVc(0);
    putK(0);
    putV(0);

    float* const shPTw = shPT[w];
    for (int t = 0; t < NCH; ++t) {
        const int cur = t & 1;
        if (t + 1 < NCH) { loadKc(t + 1); loadVc(t + 1); }
        __syncthreads();
        const short* K  = shK[cur];
        const short* Vt = shVt[cur];
        const int c0 = t * 64;

        // phase 1: all 4 score tiles (independent chains)
        f32x4 s[4] = {{0,0,0,0},{0,0,0,0},{0,0,0,0},{0,0,0,0}};
#pragma unroll
        for (int ct = 0; ct < 4; ++ct) {
            const int kc = ct * 16 + l15;
            bf16x8 kf = ldfrag(&K[SW(kc, 8 * lg)]);
            s[ct] = __builtin_amdgcn_mfma_f32_16x16x32_bf16(kf, qf0, s[ct], 0, 0, 0);
            kf = ldfrag(&K[SW(kc, 32 + 8 * lg)]);
            s[ct] = __builtin_amdgcn_mfma_f32_16x16x32_bf16(kf, qf1, s[ct], 0, 0, 0);
        }
        // phase 2: exp + mask; park f32 P in per-wave LDS; pack bf16 p-quads
        s16x4 pf[4];
#pragma unroll
        for (int ct = 0; ct < 4; ++ct) {
            const unsigned mw = *(const unsigned*)&shMask[c0 + ct * 16 + lg * 4];
            f32x4 p;
#pragma unroll
            for (int r = 0; r < 4; ++r)
                p[r] = ((mw >> (8 * r)) & 1u) ? __expf(s[ct][r] + lnInvl) : 0.f;
            *(f32x4*)&shPTw[SWF(l15, ct * 16 + lg * 4)] = p;
            u32x2 pk;
            pk[0] = pack2(p[0], p[1]);
            pk[1] = pack2(p[2], p[3]);
            pf[ct] = __builtin_bit_cast(s16x4, pk);
        }
        // phase 2b: transposed full-line nt stores (8 lanes x 16B = 128B line)
#pragma unroll
        for (int st = 0; st < 4; ++st) {
            const int rowIdx = (lane >> 3) + (st >> 1) * 8;
            const int cm     = (lane & 7) * 4 + (st & 1) * 32;
            const f32x4 pv_ = *(const f32x4*)&shPTw[SWF(rowIdx, cm)];
            __builtin_nontemporal_store(
                pv_, (f32x4*)(attnbh + (size_t)(q0 + w * 16 + rowIdx) * S_LEN + c0 + cm));
        }
        // phase 3: PV, 4 independent oacc chains x 4 k-quads (K=16 MFMA)
#pragma unroll
        for (int dt = 0; dt < 4; ++dt) {
#pragma unroll
            for (int ct = 0; ct < 4; ++ct) {
                const s16x4 af = *(const s16x4*)&Vt[SW(dt * 16 + l15, ct * 16 + 4 * lg)];
                oacc[dt] = __builtin_amdgcn_mfma_f32_16x16x16bf16_1k(af, pf[ct], oacc[dt], 0, 0, 0);
            }
        }
        if (t + 1 < NCH) { putK(cur ^ 1); putV(cur ^ 1); }
    }

    float* obase = out + ((size_t)bh * S_LEN + q0 + qrow) * DH;
#pragma unroll
    for (int dt = 0; dt < 4; ++dt)
        __builtin_nontemporal_store(oacc[dt], (f32x4*)(obase + dt * 16 + lg * 4));
}

// ---------- fallback: R11 kernel verbatim (used if ws too small) ----------
__global__ __launch_bounds__(512, 4) void sdpa_fallback(
    const float* __restrict__ q, const float* __restrict__ k,
    const float* __restrict__ v, const int* __restrict__ mask,
    float* __restrict__ out, float* __restrict__ attn)
{
    __shared__ __align__(16) short shK[2][64 * 64];
    __shared__ __align__(16) short shVt[2][64 * 64];
    __shared__ __align__(16) float shPT[8][16 * 64];
    __shared__ char shMask[S_LEN];

    const int tid  = threadIdx.x;
    const int lane = tid & 63;
    const int w    = tid >> 6;
    const int l15  = lane & 15;
    const int lg   = lane >> 4;

    const int bh = blockIdx.y;
    const int q0 = blockIdx.x * QT;
    const int b  = bh >> 4;

    const float* qbase = q + ((size_t)bh * S_LEN + q0) * DH;
    const float* kbase = k + (size_t)bh * S_LEN * DH;
    const float* vbase = v + (size_t)bh * S_LEN * DH;
    float* attnbh = attn + (size_t)bh * S_LEN * S_LEN;

    for (int i = tid; i < S_LEN; i += 512)
        shMask[i] = (char)(mask[b * S_LEN + i] != 0);

    const int qrow = w * 16 + l15;
    bf16x8 qf0, qf1;
    {
        const float* qp = qbase + qrow * DH + 8 * lg;
        const float4 a0 = *(const float4*)(qp);
        const float4 a1 = *(const float4*)(qp + 4);
        const float4 b0 = *(const float4*)(qp + 32);
        const float4 b1 = *(const float4*)(qp + 36);
        s16x8 t0, t1;
        t0[0]=f2bf(a0.x*0.125f); t0[1]=f2bf(a0.y*0.125f); t0[2]=f2bf(a0.z*0.125f); t0[3]=f2bf(a0.w*0.125f);
        t0[4]=f2bf(a1.x*0.125f); t0[5]=f2bf(a1.y*0.125f); t0[6]=f2bf(a1.z*0.125f); t0[7]=f2bf(a1.w*0.125f);
        t1[0]=f2bf(b0.x*0.125f); t1[1]=f2bf(b0.y*0.125f); t1[2]=f2bf(b0.z*0.125f); t1[3]=f2bf(b0.w*0.125f);
        t1[4]=f2bf(b1.x*0.125f); t1[5]=f2bf(b1.y*0.125f); t1[6]=f2bf(b1.z*0.125f); t1[7]=f2bf(b1.w*0.125f);
        qf0 = __builtin_bit_cast(bf16x8, t0);
        qf1 = __builtin_bit_cast(bf16x8, t1);
    }

    const int krow = tid >> 3;
    const int kd0  = (tid & 7) * 8;
    float4 ka, kb;
    auto loadK = [&](int c0) {
        const float* src = kbase + (size_t)(c0 + krow) * DH + kd0;
        ka = *(const float4*)(src);
        kb = *(const float4*)(src + 4);
    };
    auto writeK = [&](short* dst) {
        s16x8 vv;
        vv[0]=f2bf(ka.x); vv[1]=f2bf(ka.y); vv[2]=f2bf(ka.z); vv[3]=f2bf(ka.w);
        vv[4]=f2bf(kb.x); vv[5]=f2bf(kb.y); vv[6]=f2bf(kb.z); vv[7]=f2bf(kb.w);
        *(s16x8*)&dst[SW(krow, kd0)] = vv;
    };
    const int vr0 = (tid & 31) * 2;
    const int vdg = tid >> 5;
    float4 va, vb;
    auto loadV = [&](int c0) {
        const float* src = vbase + (size_t)(c0 + vr0) * DH + vdg * 4;
        va = *(const float4*)(src);
        vb = *(const float4*)(src + DH);
    };
    auto writeVt = [&](short* dst) {
        const float av[4] = {va.x, va.y, va.z, va.w};
        const float bv[4] = {vb.x, vb.y, vb.z, vb.w};
        int* dw = (int*)dst;
#pragma unroll
        for (int i = 0; i < 4; ++i) {
            const int d = vdg * 4 + i;
            dw[(d * 64 + (vr0 ^ ((d & 7) << 3))) >> 1] = (int)pack2(av[i], bv[i]);
        }
    };

    loadK(0);
    writeK(shK[0]);
    __syncthreads();

    float lacc = 0.f;
    for (int t = 0; t < NCH; ++t) {
        const int cur = t & 1;
        if (t + 1 < NCH) loadK((t + 1) * 64);
        __syncthreads();
        const short* K = shK[cur];
        const int c0 = t * 64;
        f32x4 s[4] = {{0,0,0,0},{0,0,0,0},{0,0,0,0},{0,0,0,0}};
#pragma unroll
        for (int ct = 0; ct < 4; ++ct) {
            const int kc = ct * 16 + l15;
            bf16x8 kf = ldfrag(&K[SW(kc, 8 * lg)]);
            s[ct] = __builtin_amdgcn_mfma_f32_16x16x32_bf16(kf, qf0, s[ct], 0, 0, 0);
            kf = ldfrag(&K[SW(kc, 32 + 8 * lg)]);
            s[ct] = __builtin_amdgcn_mfma_f32_16x16x32_bf16(kf, qf1, s[ct], 0, 0, 0);
        }
#pragma unroll
        for (int ct = 0; ct < 4; ++ct) {
            const unsigned mw = *(const unsigned*)&shMask[c0 + ct * 16 + lg * 4];
#pragma unroll
            for (int r = 0; r < 4; ++r)
                lacc += ((mw >> (8 * r)) & 1u) ? __expf(s[ct][r]) : 0.f;
        }
        if (t + 1 < NCH) writeK(shK[cur ^ 1]);
    }
    lacc += __shfl_xor(lacc, 16);
    lacc += __shfl_xor(lacc, 32);
    const float lnInvl = -__logf(lacc);

    f32x4 oacc[4] = {{0,0,0,0},{0,0,0,0},{0,0,0,0},{0,0,0,0}};
    loadK(0);
    loadV(0);
    writeK(shK[0]);
    writeVt(shVt[0]);

    float* const shPTw = shPT[w];
    for (int t = 0; t < NCH; ++t) {
        const int cur = t & 1;
        if (t + 1 < NCH) { loadK((t + 1) * 64); loadV((t + 1) * 64); }
        __syncthreads();
        const short* K  = shK[cur];
        const short* Vt = shVt[cur];
        const int c0 = t * 64;

        f32x4 s[4] = {{0,0,0,0},{0,0,0,0},{0,0,0,0},{0,0,0,0}};
#pragma unroll
        for (int ct = 0; ct < 4; ++ct) {
            const int kc = ct * 16 + l15;
            bf16x8 kf = ldfrag(&K[SW(kc, 8 * lg)]);
            s[ct] = __builtin_amdgcn_mfma_f32_16x16x32_bf16(kf, qf0, s[ct], 0, 0, 0);
            kf = ldfrag(&K[SW(kc, 32 + 8 * lg)]);
            s[ct] = __builtin_amdgcn_mfma_f32_16x16x32_bf16(kf, qf1, s[ct], 0, 0, 0);
        }
        s16x4 pf[4];
#pragma unroll
        for (int ct = 0; ct < 4; ++ct) {
            const unsigned mw = *(const unsigned*)&shMask[c0 + ct * 16 + lg * 4];
            f32x4 p;
#pragma unroll
            for (int r = 0; r < 4; ++r)
                p[r] = ((mw >> (8 * r)) & 1u) ? __expf(s[ct][r] + lnInvl) : 0.f;
            *(f32x4*)&shPTw[SWF(l15, ct * 16 + lg * 4)] = p;
            u32x2 pk;
            pk[0] = pack2(p[0], p[1]);
            pk[1] = pack2(p[2], p[3]);
            pf[ct] = __builtin_bit_cast(s16x4, pk);
        }
#pragma unroll
        for (int st = 0; st < 4; ++st) {
            const int rowIdx = (lane >> 3) + (st >> 1) * 8;
            const int cm     = (lane & 7) * 4 + (st & 1) * 32;
            const f32x4 pv_ = *(const f32x4*)&shPTw[SWF(rowIdx, cm)];
            __builtin_nontemporal_store(
                pv_, (f32x4*)(attnbh + (size_t)(q0 + w * 16 + rowIdx) * S_LEN + c0 + cm));
        }
#pragma unroll
        for (int dt = 0; dt < 4; ++dt) {
#pragma unroll
            for (int ct = 0; ct < 4; ++ct) {
                const s16x4 af = *(const s16x4*)&Vt[SW(dt * 16 + l15, ct * 16 + 4 * lg)];
                oacc[dt] = __builtin_amdgcn_mfma_f32_16x16x16bf16_1k(af, pf[ct], oacc[dt], 0, 0, 0);
            }
        }
        if (t + 1 < NCH) { writeK(shK[cur ^ 1]); writeVt(shVt[cur ^ 1]); }
    }

    float* obase = out + ((size_t)bh * S_LEN + q0 + qrow) * DH;
#pragma unroll
    for (int dt = 0; dt < 4; ++dt)
        __builtin_nontemporal_store(oacc[dt], (f32x4*)(obase + dt * 16 + lg * 4));
}

extern "C" void kernel_launch(void* const* d_in, const int* in_sizes, int n_in,
                              void* d_out, int out_size, void* d_ws, size_t ws_size,
                              hipStream_t stream)
{
    const float* q    = (const float*)d_in[0];
    const float* k    = (const float*)d_in[1];
    const float* v    = (const float*)d_in[2];
    const int*   mask = (const int*)d_in[3];
    float* out  = (float*)d_out;
    float* attn = out + (size_t)2 * 16 * 2048 * 64;   // (out, attn) concatenated

    const size_t WS_NEED = (size_t)2 * 32 * 32 * 4096 * sizeof(short);  // 16 MB
    dim3 grid(S_LEN / QT, 2 * 16);   // 2D grid (x=qtile, y=bh) — pinned (R12)

    if (ws_size >= WS_NEED) {
        short* wsK  = (short*)d_ws;
        short* wsVt = wsK + (size_t)32 * 32 * 4096;
        prep_kernel<<<dim3(1024), dim3(256), 0, stream>>>(k, v, wsK, wsVt);
        sdpa_main<<<grid, dim3(512), 0, stream>>>(q, wsK, wsVt, mask, out, attn);
    } else {
        sdpa_fallback<<<grid, dim3(512), 0, stream>>>(q, k, v, mask, out, attn);
    }
}